// Round 6
// baseline (1385.090 us; speedup 1.0000x reference)
//
#include <hip/hip_runtime.h>
#include <math.h>

// GRU-RCN bf16 MFMA. B=8,T=16,C=Oh=64,HxW=56x56, 3x3 SAME.
// Round-6 structure:
//  * conv blocks: 4 waves SPLIT M (1 output row each), SHARE the N-slice
//    -> weight fragments 4-way L1-shared (B traffic per block /4).
//  * co-dispatch: stepA = convU(t) || convW(t+1); stepB = convC(t) || xprep(t+2)
//    (independent roles in one launch; x-path off the critical path).
// Layouts:
//  padded imgs (xpad[2]/hpad/rhpad): bf16 [b][58][66][64ci], 16B ci-slices
//    XOR-swizzled by (col&7) -> conflict-free ds_read_b128.
//  wcat: bf16 [plane(ky*3+kx)][o][ci] (W:192ch, U:128ch, C:64ch)
//  wx[2 slots]: bf16 [b][y56][px64][192]; zb/hstate: f32 [b][y][px64][64]

#define PIX 4224                   // 66*64 u16 per padded row
#define PIMG 244992                // 58*PIX u16 per padded image
#define BIMG ((size_t)8 * PIMG)    // u16 per image set (8 batches)
#define WXS ((size_t)5505024)      // u16 per wx slot: 8*56*64*192
#define HL_OFF ((size_t)25690112)  // 8*16*64*3136 floats

typedef unsigned short u16;
typedef __attribute__((ext_vector_type(8))) __bf16 bf16x8;
typedef __attribute__((ext_vector_type(4))) float f32x4;

__device__ __forceinline__ float bf2f(u16 u) {
  unsigned v = ((unsigned)u) << 16;
  float f;
  __builtin_memcpy(&f, &v, 4);
  return f;
}
__device__ __forceinline__ u16 f2bf(float f) {
  unsigned u;
  __builtin_memcpy(&u, &f, 4);
  u = (u + 0x7FFFu + ((u >> 16) & 1u)) >> 16;  // RNE
  return (u16)u;
}
__device__ __forceinline__ void gll16(const void* g, void* l) {
  __builtin_amdgcn_global_load_lds(
      (const __attribute__((address_space(1))) void*)g,
      (__attribute__((address_space(3))) void*)l, 16, 0, 0);
}

// ---- conv core: block = 4 rows(y0..y0+3) x 32px x NF*16ch (ch shared) ------
// wave wv computes row y0+wv. Stage: 6 padded rows y0..y0+5, px x0..x0+33.
template <int NF>
__device__ __forceinline__ void conv_core(const u16* __restrict__ img,
                                          const u16* __restrict__ wb,
                                          const int NCH, const int y0,
                                          const int x0, const int n0,
                                          u16* stage, f32x4 (&acc)[2][NF]) {
  const int lane = threadIdx.x & 63;
  const int wv = threadIdx.x >> 6;

  // stage 6 rows x 34 px x 128B (per row: 4x1KB + 256B chunks)
  for (int i = wv; i < 30; i += 4) {
    const int r = i / 5, k = i % 5;
    const u16* g = img + (size_t)(y0 + r) * PIX + x0 * 64 + k * 512 + lane * 8;
    u16* l = stage + r * 2176 + k * 512;
    if (k < 4 || lane < 16) gll16(g, l);
  }
  asm volatile("s_waitcnt vmcnt(0)" ::: "memory");
  __syncthreads();

  const u16* wrow = wb + (size_t)(n0 + (lane & 15)) * 64 + ((lane >> 4) * 8);
#pragma unroll 1
  for (int kk = 0; kk < 6; ++kk) {
    const int ky = kk >> 1, kc = kk & 1;
    bf16x8 bf[3][NF];
#pragma unroll
    for (int kx = 0; kx < 3; ++kx)
#pragma unroll
      for (int nf = 0; nf < NF; ++nf)
        bf[kx][nf] = *(const bf16x8*)(wrow + (size_t)(ky * 3 + kx) * NCH * 64 +
                                      nf * 1024 + kc * 32);
    bf16x8 af[2][3];
#pragma unroll
    for (int mf = 0; mf < 2; ++mf)
#pragma unroll
      for (int kx = 0; kx < 3; ++kx) {
        const int p = mf * 16 + (lane & 15) + kx;
        const int sl = (kc * 4 + (lane >> 4)) ^ (p & 7);
        af[mf][kx] =
            *(const bf16x8*)(stage + ((wv + ky) * 34 + p) * 64 + sl * 8);
      }
#pragma unroll
    for (int kx = 0; kx < 3; ++kx)
#pragma unroll
      for (int mf = 0; mf < 2; ++mf)
#pragma unroll
        for (int nf = 0; nf < NF; ++nf)
          acc[mf][nf] = __builtin_amdgcn_mfma_f32_16x16x32_bf16(
              af[mf][kx], bf[kx][nf], acc[mf][nf], 0, 0, 0);
  }
}

// ---- unit decoders: u in [0,896) = (xn:8)(yq:14)(b:8) ----------------------
// xn = u&7: x0=(xn&1)*32, nslice=(xn>>1); yq=(u>>3)%14; b=u/112

__device__ __forceinline__ void do_convW(const u16* __restrict__ xp,
                                         const u16* __restrict__ wcat,
                                         u16* __restrict__ wx, int u,
                                         u16* stage) {
  const int xn = u & 7;
  const int x0 = (xn & 1) * 32, n0 = (xn >> 1) * 48;
  const int yq = (u >> 3) % 14, b = u / 112;
  const int y0 = yq * 4;
  const int lane = threadIdx.x & 63, wv = threadIdx.x >> 6;
  f32x4 acc[2][3];
#pragma unroll
  for (int mf = 0; mf < 2; ++mf)
#pragma unroll
    for (int nf = 0; nf < 3; ++nf) acc[mf][nf] = (f32x4){0.f, 0.f, 0.f, 0.f};
  conv_core<3>(xp + (size_t)b * PIMG, wcat, 192, y0, x0, n0, stage, acc);

  const int y = y0 + wv;
  const size_t rowb = ((size_t)(b * 56) + y) * 64;
#pragma unroll
  for (int mf = 0; mf < 2; ++mf)
#pragma unroll
    for (int nf = 0; nf < 3; ++nf) {
      const int n = n0 + nf * 16 + (lane & 15);
#pragma unroll
      for (int r = 0; r < 4; ++r) {
        const int px = x0 + mf * 16 + 4 * (lane >> 4) + r;
        wx[(rowb + px) * 192 + n] = f2bf(acc[mf][nf][r]);
      }
    }
}

__device__ __forceinline__ void do_convU(
    const u16* __restrict__ hpad, const u16* __restrict__ ucat,
    const u16* __restrict__ wx, const float* __restrict__ hstate,
    float* __restrict__ zb, u16* __restrict__ rhpad, int u, u16* stage) {
  const int xn = u & 7;
  const int x0 = (xn & 1) * 32, n0 = (xn >> 1) * 32;
  const int yq = (u >> 3) % 14, b = u / 112;
  const int y0 = yq * 4;
  const int lane = threadIdx.x & 63, wv = threadIdx.x >> 6;
  f32x4 acc[2][2];
#pragma unroll
  for (int mf = 0; mf < 2; ++mf)
#pragma unroll
    for (int nf = 0; nf < 2; ++nf) acc[mf][nf] = (f32x4){0.f, 0.f, 0.f, 0.f};
  conv_core<2>(hpad + (size_t)b * PIMG, ucat, 128, y0, x0, n0, stage, acc);

  const int y = y0 + wv;
  const size_t rowb = ((size_t)(b * 56) + y) * 64;
#pragma unroll
  for (int mf = 0; mf < 2; ++mf)
#pragma unroll
    for (int nf = 0; nf < 2; ++nf) {
      const int n = n0 + nf * 16 + (lane & 15);
#pragma unroll
      for (int r = 0; r < 4; ++r) {
        const int px = x0 + mf * 16 + 4 * (lane >> 4) + r;
        if (px < 56) {
          float a = bf2f(wx[(rowb + px) * 192 + n]) + acc[mf][nf][r];
          float s = 1.f / (1.f + __expf(-a));
          if (n0 < 64) {  // block-uniform branch
            zb[(rowb + px) * 64 + n] = s;
          } else {
            const int ci = n - 64;
            float rh = s * hstate[(rowb + px) * 64 + ci];
            const int gx = px + 1;
            rhpad[(size_t)b * PIMG + (size_t)(y + 1) * PIX + gx * 64 +
                  (((ci >> 3) ^ (gx & 7)) << 3) + (ci & 7)] = f2bf(rh);
          }
        }
      }
    }
}

__device__ __forceinline__ void do_convC(
    const u16* __restrict__ rhpad, const u16* __restrict__ ccat,
    const u16* __restrict__ wx, const float* __restrict__ zb,
    float* __restrict__ hstate, u16* __restrict__ hpad,
    float* __restrict__ out, int t, int u, u16* stage, float (*ldt)[16][33]) {
  const int xn = u & 7;
  const int x0 = (xn & 1) * 32, n0 = (xn >> 1) * 16;
  const int yq = (u >> 3) % 14, b = u / 112;
  const int y0 = yq * 4;
  const int lane = threadIdx.x & 63, wv = threadIdx.x >> 6;
  f32x4 acc[2][1];
  acc[0][0] = (f32x4){0.f, 0.f, 0.f, 0.f};
  acc[1][0] = (f32x4){0.f, 0.f, 0.f, 0.f};
  conv_core<1>(rhpad + (size_t)b * PIMG, ccat, 64, y0, x0, n0, stage, acc);

  const int y = y0 + wv;
  const size_t rowb = ((size_t)(b * 56) + y) * 64;
  const int n = n0 + (lane & 15);
#pragma unroll
  for (int mf = 0; mf < 2; ++mf)
#pragma unroll
    for (int r = 0; r < 4; ++r) {
      const int px = x0 + mf * 16 + 4 * (lane >> 4) + r;
      if (px < 56) {
        float a = bf2f(wx[(rowb + px) * 192 + 128 + n]) + acc[mf][0][r];
        float htil = tanhf(a);
        float z = zb[(rowb + px) * 64 + n];
        float ho = hstate[(rowb + px) * 64 + n];
        float hn = fmaf(z, htil - ho, ho);
        hstate[(rowb + px) * 64 + n] = hn;
        const int gx = px + 1;
        hpad[(size_t)b * PIMG + (size_t)(y + 1) * PIX + gx * 64 +
             (((n >> 3) ^ (gx & 7)) << 3) + (n & 7)] = f2bf(hn);
        ldt[wv][lane & 15][mf * 16 + 4 * (lane >> 4) + r] = hn;
      }
    }
  __syncthreads();
  const int xl = lane & 31;
  const int px = x0 + xl;
  if (px < 56) {
#pragma unroll
    for (int cc = 0; cc < 8; ++cc) {
      const int ch = (lane >> 5) * 8 + cc;
      float v = ldt[wv][ch][xl];
      out[(((size_t)(b * 16 + t)) * 64 + n0 + ch) * 3136 + y * 56 + px] = v;
      if (t == 15)
        out[HL_OFF + ((size_t)(b * 64) + n0 + ch) * 3136 + y * 56 + px] = v;
    }
  }
}

__device__ __forceinline__ void xprep_row(const float* __restrict__ x,
                                          u16* __restrict__ dst, int t,
                                          int row, float (*tx)[57]) {
  const int y = row % 56, b = row / 56;
  const int tid = threadIdx.x;
  for (int i = tid; i < 64 * 56; i += 256) {
    int ci = i / 56, px = i % 56;
    tx[ci][px] = x[((size_t)(b * 16 + t) * 64 + ci) * 3136 + y * 56 + px];
  }
  __syncthreads();
  const size_t pb = (size_t)b * PIMG + (size_t)(y + 1) * PIX;
  for (int i = tid; i < 56 * 64; i += 256) {
    int px = i / 64, ci = i % 64;
    int gx = px + 1;
    dst[pb + gx * 64 + (((ci >> 3) ^ (gx & 7)) << 3) + (ci & 7)] =
        f2bf(tx[ci][px]);
  }
}

// ---- standalone prep kernels ------------------------------------------------
__global__ __launch_bounds__(256) void wprep_k(const float* __restrict__ W,
                                               const float* __restrict__ U,
                                               const float* __restrict__ C,
                                               u16* __restrict__ wcat) {
  int i = blockIdx.x * 256 + threadIdx.x;
  if (i >= 221184) return;
  float v;
  if (i < 110592) {
    int plane = i / 12288, rem = i % 12288, o = rem / 64, ci = rem % 64;
    v = W[(size_t)(o * 64 + ci) * 9 + plane];
  } else if (i < 184320) {
    int j = i - 110592;
    int plane = j / 8192, rem = j % 8192, o = rem / 64, ci = rem % 64;
    v = U[(size_t)(o * 64 + ci) * 9 + plane];
  } else {
    int j = i - 184320;
    int plane = j / 4096, rem = j % 4096, o = rem / 64, ci = rem % 64;
    v = C[(size_t)(o * 64 + ci) * 9 + plane];
  }
  wcat[i] = f2bf(v);
}

__global__ __launch_bounds__(256) void hinit_k(const float* __restrict__ h,
                                               u16* __restrict__ hpad,
                                               float* __restrict__ hstate) {
  __shared__ float t[64][57];
  const int y = blockIdx.x, b = blockIdx.y;
  const int tid = threadIdx.x;
  for (int i = tid; i < 64 * 56; i += 256) {
    int ci = i / 56, xx = i % 56;
    t[ci][xx] = h[((size_t)(b * 64) + ci) * 3136 + y * 56 + xx];
  }
  __syncthreads();
  const size_t pb = (size_t)b * PIMG + (size_t)(y + 1) * PIX;
  const size_t sb = ((size_t)(b * 56) + y) * 64;
  for (int i = tid; i < 56 * 64; i += 256) {
    int px = i / 64, ci = i % 64;
    float v = t[ci][px];
    int gx = px + 1;
    hpad[pb + gx * 64 + (((ci >> 3) ^ (gx & 7)) << 3) + (ci & 7)] = f2bf(v);
    hstate[(sb + px) * 64 + ci] = v;
  }
}

__global__ __launch_bounds__(256) void xprep2_k(const float* __restrict__ x,
                                                u16* __restrict__ xpad) {
  __shared__ float tt[64][57];
  const int t = blockIdx.z;  // 0,1 -> slots 0,1
  xprep_row(x, xpad + (size_t)(t & 1) * BIMG, t,
            blockIdx.y * 56 + blockIdx.x, tt);
}

// ---- step kernels (role-split co-dispatch) ----------------------------------
__global__ __launch_bounds__(256) void stepA_k(
    const u16* __restrict__ xpad, const u16* __restrict__ hpad,
    const u16* __restrict__ wcat, u16* __restrict__ wxr,
    const float* __restrict__ hstate, float* __restrict__ zb,
    u16* __restrict__ rhpad, int t, int uoff) {
  __shared__ __align__(16) u16 stage[13056];
  const int id = blockIdx.x + uoff;
  if (id < 896) {
    do_convU(hpad, wcat + 110592, wxr + (size_t)(t & 1) * WXS, hstate, zb,
             rhpad, id, stage);
  } else if (t + 1 < 16) {
    do_convW(xpad + (size_t)((t + 1) & 1) * BIMG, wcat,
             wxr + (size_t)((t + 1) & 1) * WXS, id - 896, stage);
  }
}

__global__ __launch_bounds__(256) void stepB_k(
    const float* __restrict__ x, u16* __restrict__ xpad,
    const u16* __restrict__ rhpad, const u16* __restrict__ wcat,
    const u16* __restrict__ wxr, const float* __restrict__ zb,
    float* __restrict__ hstate, u16* __restrict__ hpad,
    float* __restrict__ out, int t) {
  __shared__ __align__(16) u16 stage[13056];
  __shared__ float ldt[4][16][33];
  const int id = blockIdx.x;
  if (id < 896) {
    do_convC(rhpad, wcat + 184320, wxr + (size_t)(t & 1) * WXS, zb, hstate,
             hpad, out, t, id, stage, ldt);
  } else if (t + 2 < 16) {
    xprep_row(x, xpad + (size_t)((t + 2) & 1) * BIMG, t + 2, id - 896,
              (float(*)[57])stage);
  }
}

extern "C" void kernel_launch(void* const* d_in, const int* in_sizes, int n_in,
                              void* d_out, int out_size, void* d_ws,
                              size_t ws_size, hipStream_t stream) {
  const float* x = (const float*)d_in[0];
  const float* h = (const float*)d_in[1];
  const float* W = (const float*)d_in[2];
  const float* U = (const float*)d_in[3];
  const float* C = (const float*)d_in[4];
  float* out = (float*)d_out;

  u16* ws_u = (u16*)d_ws;
  u16* xpad = ws_u;                    // 2 slots x BIMG
  u16* hpad = xpad + 2 * BIMG;         // BIMG
  u16* rhpad = hpad + BIMG;            // BIMG
  u16* wcat = rhpad + BIMG;            // 221,184
  u16* wxr = wcat + 221184;            // 2 slots x WXS
  float* zb = (float*)(wxr + 2 * WXS); // 1,835,008 f32
  float* hstate = zb + 1835008;        // 1,835,008 f32

  // zero the 4 padded images (borders must stay 0)
  hipMemsetAsync(d_ws, 0, (size_t)4 * BIMG * sizeof(u16), stream);
  wprep_k<<<864, 256, 0, stream>>>(W, U, C, wcat);
  hinit_k<<<dim3(56, 8), 256, 0, stream>>>(h, hpad, hstate);
  xprep2_k<<<dim3(56, 8, 2), 256, 0, stream>>>(x, xpad);
  // prologue: convW(0) only (blocks get ids >= 896 via uoff)
  stepA_k<<<896, 256, 0, stream>>>(xpad, hpad, wcat, wxr, hstate, zb, rhpad,
                                   -1, 896);
  for (int t = 0; t < 16; ++t) {
    stepA_k<<<1792, 256, 0, stream>>>(xpad, hpad, wcat, wxr, hstate, zb,
                                      rhpad, t, 0);
    stepB_k<<<1344, 256, 0, stream>>>(x, xpad, rhpad, wcat, wxr, zb, hstate,
                                      hpad, out, t);
  }
}

// Round 7
// 1285.228 us; speedup vs baseline: 1.0777x; 1.0777x over previous
//
#include <hip/hip_runtime.h>
#include <math.h>

// GRU-RCN bf16 MFMA, fused dual-source convs. B=8,T=16,C=Oh=64,56x56,3x3 SAME.
// Per step t (2 dispatches, sequential h-dependency):
//   stepA: a = conv(x_t,W_zr) + conv(h,U_zr)  [12-phase dual-source MFMA core]
//          -> z (fp16 zbuf), rh (bf16 rhpad)       [wx buffer ELIMINATED]
//   stepB: a = conv(x_t,W_c) + conv(rh,C); h' = (1-z)h + z tanh(a)
//          -> hstate f32, hpad bf16, out; co-dispatched xprep(t+1).
// Layouts:
//   padded imgs (xpad[2]/hpad/rhpad): bf16 [b][58][66][64ci], 16B ci-slices
//     XOR-swizzled by (col&7) -> conflict-free ds_read_b128.
//   wcat: bf16 [plane(ky*3+kx)][o][ci] (W:192ch, U:128ch, C:64ch)
//   zbuf: fp16 [b][y][px64][64]; hstate: f32 [b][y][px64][64]

#define PIX 4224                   // 66*64 u16 per padded row
#define PIMG 244992                // 58*PIX u16 per padded image
#define BIMG ((size_t)8 * PIMG)    // u16 per image set (8 batches)
#define HL_OFF ((size_t)25690112)  // 8*16*64*3136 floats
#define STRIP 13056                // u16 per staged 6-row strip (6*34*64)

typedef unsigned short u16;
typedef __attribute__((ext_vector_type(8))) __bf16 bf16x8;
typedef __attribute__((ext_vector_type(4))) float f32x4;

__device__ __forceinline__ float bf2f(u16 u) {
  unsigned v = ((unsigned)u) << 16;
  float f;
  __builtin_memcpy(&f, &v, 4);
  return f;
}
__device__ __forceinline__ u16 f2bf(float f) {
  unsigned u;
  __builtin_memcpy(&u, &f, 4);
  u = (u + 0x7FFFu + ((u >> 16) & 1u)) >> 16;  // RNE
  return (u16)u;
}
__device__ __forceinline__ void gll16(const void* g, void* l) {
  __builtin_amdgcn_global_load_lds(
      (const __attribute__((address_space(1))) void*)g,
      (__attribute__((address_space(3))) void*)l, 16, 0, 0);
}

// ---- dual-source conv core --------------------------------------------------
// block = 4 rows x 32px x NF*16ch (n-slice shared by all 4 waves; wave = row).
// 12 phases: p<6 -> (img0, wb0/NCH0); p>=6 -> (img1, wb1/NCH1). Both sources
// accumulate into the SAME acc (the GRU pre-activations are sums of 2 convs).
// B frags prefetched 1-deep; phase-0 B issued before the stage-wait.
template <int NF>
__device__ __forceinline__ void conv2_core(
    const u16* __restrict__ img0, const u16* __restrict__ img1,
    const u16* __restrict__ wb0, const u16* __restrict__ wb1, const int NCH0,
    const int NCH1, const int y0, const int x0, u16* stage,
    f32x4 (&acc)[2][NF]) {
  const int lane = threadIdx.x & 63;
  const int wv = threadIdx.x >> 6;
  const u16* wr0 = wb0 + (size_t)(lane & 15) * 64 + (lane >> 4) * 8;
  const u16* wr1 = wb1 + (size_t)(lane & 15) * 64 + (lane >> 4) * 8;

  bf16x8 bcur[3][NF], bnxt[3][NF];
#pragma unroll
  for (int kx = 0; kx < 3; ++kx)
#pragma unroll
    for (int nf = 0; nf < NF; ++nf)
      bcur[kx][nf] =
          *(const bf16x8*)(wr0 + (size_t)(kx * NCH0) * 64 + nf * 1024);

  // stage both strips: rows y0..y0+5, padded cols x0..x0+33 (34px x 128B)
  for (int i = wv; i < 60; i += 4) {
    const int sp = i / 30, j = i % 30, r = j / 5, k = j % 5;
    const u16* g = (sp ? img1 : img0) + (size_t)(y0 + r) * PIX + x0 * 64 +
                   k * 512 + lane * 8;
    u16* l = stage + sp * STRIP + r * 2176 + k * 512;
    if (k < 4 || lane < 16) gll16(g, l);
  }
  asm volatile("s_waitcnt vmcnt(0)" ::: "memory");
  __syncthreads();

#pragma unroll 1
  for (int p = 0; p < 12; ++p) {
    if (p < 11) {
      const int pn = p + 1;
      const int ky = (pn % 6) >> 1, kc = pn & 1;
      const u16* w = (pn < 6) ? wr0 : wr1;
      const int NC = (pn < 6) ? NCH0 : NCH1;
#pragma unroll
      for (int kx = 0; kx < 3; ++kx)
#pragma unroll
        for (int nf = 0; nf < NF; ++nf)
          bnxt[kx][nf] = *(const bf16x8*)(w + (size_t)((ky * 3 + kx) * NC) * 64 +
                                          nf * 1024 + kc * 32);
    }
    const int ky = (p % 6) >> 1, kc = p & 1;
    const int soff = (p < 6) ? 0 : STRIP;
    bf16x8 af[2][3];
#pragma unroll
    for (int mf = 0; mf < 2; ++mf)
#pragma unroll
      for (int kx = 0; kx < 3; ++kx) {
        const int pp = mf * 16 + (lane & 15) + kx;
        const int sl = (kc * 4 + (lane >> 4)) ^ (pp & 7);
        af[mf][kx] =
            *(const bf16x8*)(stage + soff + ((wv + ky) * 34 + pp) * 64 + sl * 8);
      }
#pragma unroll
    for (int kx = 0; kx < 3; ++kx)
#pragma unroll
      for (int mf = 0; mf < 2; ++mf)
#pragma unroll
        for (int nf = 0; nf < NF; ++nf)
          acc[mf][nf] = __builtin_amdgcn_mfma_f32_16x16x32_bf16(
              af[mf][kx], bcur[kx][nf], acc[mf][nf], 0, 0, 0);
#pragma unroll
    for (int kx = 0; kx < 3; ++kx)
#pragma unroll
      for (int nf = 0; nf < NF; ++nf) bcur[kx][nf] = bnxt[kx][nf];
  }
}

// ---- prep -------------------------------------------------------------------
__global__ __launch_bounds__(256) void wprep_k(const float* __restrict__ W,
                                               const float* __restrict__ U,
                                               const float* __restrict__ C,
                                               u16* __restrict__ wcat) {
  int i = blockIdx.x * 256 + threadIdx.x;
  if (i >= 221184) return;
  float v;
  if (i < 110592) {
    int plane = i / 12288, rem = i % 12288, o = rem / 64, ci = rem % 64;
    v = W[(size_t)(o * 64 + ci) * 9 + plane];
  } else if (i < 184320) {
    int j = i - 110592;
    int plane = j / 8192, rem = j % 8192, o = rem / 64, ci = rem % 64;
    v = U[(size_t)(o * 64 + ci) * 9 + plane];
  } else {
    int j = i - 184320;
    int plane = j / 4096, rem = j % 4096, o = rem / 64, ci = rem % 64;
    v = C[(size_t)(o * 64 + ci) * 9 + plane];
  }
  wcat[i] = f2bf(v);
}

__global__ __launch_bounds__(256) void hinit_k(const float* __restrict__ h,
                                               u16* __restrict__ hpad,
                                               float* __restrict__ hstate) {
  __shared__ float t[64][57];
  const int y = blockIdx.x, b = blockIdx.y;
  const int tid = threadIdx.x;
  for (int i = tid; i < 64 * 56; i += 256) {
    int ci = i / 56, xx = i % 56;
    t[ci][xx] = h[((size_t)(b * 64) + ci) * 3136 + y * 56 + xx];
  }
  __syncthreads();
  const size_t pb = (size_t)b * PIMG + (size_t)(y + 1) * PIX;
  const size_t sb = ((size_t)(b * 56) + y) * 64;
  for (int i = tid; i < 56 * 64; i += 256) {
    int px = i / 64, ci = i % 64;
    float v = t[ci][px];
    int gx = px + 1;
    hpad[pb + gx * 64 + (((ci >> 3) ^ (gx & 7)) << 3) + (ci & 7)] = f2bf(v);
    hstate[(sb + px) * 64 + ci] = v;
  }
}

__device__ __forceinline__ void xprep_row(const float* __restrict__ x,
                                          u16* __restrict__ dst, int t,
                                          int row, float (*tx)[57]) {
  const int y = row % 56, b = row / 56;
  const int tid = threadIdx.x;
  for (int i = tid; i < 64 * 56; i += 256) {
    int ci = i / 56, px = i % 56;
    tx[ci][px] = x[((size_t)(b * 16 + t) * 64 + ci) * 3136 + y * 56 + px];
  }
  __syncthreads();
  const size_t pb = (size_t)b * PIMG + (size_t)(y + 1) * PIX;
  for (int i = tid; i < 56 * 64; i += 256) {
    int px = i / 64, ci = i % 64;
    int gx = px + 1;
    dst[pb + gx * 64 + (((ci >> 3) ^ (gx & 7)) << 3) + (ci & 7)] =
        f2bf(tx[ci][px]);
  }
}

__global__ __launch_bounds__(256) void xprep0_k(const float* __restrict__ x,
                                                u16* __restrict__ xpad) {
  __shared__ float tt[64][57];
  xprep_row(x, xpad, 0, blockIdx.x, tt);
}

// ---- stepA: z & r*h ---------------------------------------------------------
// u decode: xn=u&7 -> x0=(xn&1)*32, slice s=xn>>1 (32ch); yq=(u>>3)%14; b=u/112
// s<2: z-channels s*32..; s>=2: r-channels (s-2)*32..
__global__ __launch_bounds__(256) void stepA_k(
    const u16* __restrict__ xpad, const u16* __restrict__ hpad,
    const u16* __restrict__ wcat, _Float16* __restrict__ zbuf,
    u16* __restrict__ rhpad) {
  __shared__ __align__(16) u16 stage[2 * STRIP];
  const int u = blockIdx.x;
  const int xn = u & 7, x0 = (xn & 1) * 32, s = xn >> 1;
  const int yq = (u >> 3) % 14, y0 = yq * 4, b = u / 112;
  const int lane = threadIdx.x & 63, wv = threadIdx.x >> 6;
  const int oo = (s < 2) ? s * 32 : 64 + (s - 2) * 32;

  f32x4 acc[2][2];
#pragma unroll
  for (int mf = 0; mf < 2; ++mf)
#pragma unroll
    for (int nf = 0; nf < 2; ++nf) acc[mf][nf] = (f32x4){0.f, 0.f, 0.f, 0.f};
  conv2_core<2>(xpad + (size_t)b * PIMG, hpad + (size_t)b * PIMG,
                wcat + (size_t)oo * 64, wcat + 110592 + (size_t)oo * 64, 192,
                128, y0, x0, stage, acc);

  const int y = y0 + wv;
  const size_t rowb = ((size_t)(b * 56) + y) * 64;
#pragma unroll
  for (int mf = 0; mf < 2; ++mf)
#pragma unroll
    for (int nf = 0; nf < 2; ++nf) {
      const int nl = nf * 16 + (lane & 15);
#pragma unroll
      for (int r = 0; r < 4; ++r) {
        const int px = x0 + mf * 16 + 4 * (lane >> 4) + r;
        if (px < 56) {
          const float sg = 1.f / (1.f + __expf(-acc[mf][nf][r]));
          if (s < 2) {
            zbuf[(rowb + px) * 64 + s * 32 + nl] = (_Float16)sg;
          } else {
            const int ci = (s - 2) * 32 + nl;
            const int cp = mf * 16 + 4 * (lane >> 4) + r + 1;  // strip col
            const float hv =
                bf2f(stage[STRIP + ((wv + 1) * 34 + cp) * 64 +
                           (((ci >> 3) ^ (cp & 7)) << 3) + (ci & 7)]);
            const int gx = px + 1;
            rhpad[(size_t)b * PIMG + (size_t)(y + 1) * PIX + gx * 64 +
                  (((ci >> 3) ^ (gx & 7)) << 3) + (ci & 7)] = f2bf(sg * hv);
          }
        }
      }
    }
}

// ---- stepB: h_new = (1-z)h + z tanh(conv(x,Wc)+conv(rh,C)); + xprep(t+1) ----
__global__ __launch_bounds__(256) void stepB_k(
    const float* __restrict__ x, u16* __restrict__ xpad_nxt,
    const u16* __restrict__ xpad_cur, const u16* __restrict__ rhpad,
    const u16* __restrict__ wcat, const _Float16* __restrict__ zbuf,
    float* __restrict__ hstate, u16* __restrict__ hpad,
    float* __restrict__ out, int t) {
  __shared__ __align__(16) u16 stage[2 * STRIP];
  const int id = blockIdx.x;
  if (id >= 896) {  // xprep role for t+1
    xprep_row(x, xpad_nxt, t + 1, id - 896, (float(*)[57])stage);
    return;
  }
  const int xn = id & 7, x0 = (xn & 1) * 32, s = xn >> 1;  // 16ch slices
  const int yq = (id >> 3) % 14, y0 = yq * 4, b = id / 112;
  const int lane = threadIdx.x & 63, wv = threadIdx.x >> 6;

  f32x4 acc[2][1];
  acc[0][0] = (f32x4){0.f, 0.f, 0.f, 0.f};
  acc[1][0] = (f32x4){0.f, 0.f, 0.f, 0.f};
  conv2_core<1>(xpad_cur + (size_t)b * PIMG, rhpad + (size_t)b * PIMG,
                wcat + (size_t)(128 + s * 16) * 64,
                wcat + 184320 + (size_t)(s * 16) * 64, 192, 64, y0, x0, stage,
                acc);

  const int y = y0 + wv;
  const size_t rowb = ((size_t)(b * 56) + y) * 64;
  const int n = s * 16 + (lane & 15);
  float hnv[2][4];
#pragma unroll
  for (int mf = 0; mf < 2; ++mf)
#pragma unroll
    for (int r = 0; r < 4; ++r) {
      const int px = x0 + mf * 16 + 4 * (lane >> 4) + r;
      hnv[mf][r] = 0.f;
      if (px < 56) {
        const float htil = tanhf(acc[mf][0][r]);
        const float z = (float)zbuf[(rowb + px) * 64 + n];
        const float ho = hstate[(rowb + px) * 64 + n];
        const float hn = fmaf(z, htil - ho, ho);
        hstate[(rowb + px) * 64 + n] = hn;
        const int gx = px + 1;
        hpad[(size_t)b * PIMG + (size_t)(y + 1) * PIX + gx * 64 +
             (((n >> 3) ^ (gx & 7)) << 3) + (n & 7)] = f2bf(hn);
        hnv[mf][r] = hn;
      }
    }
  __syncthreads();  // all stage reads done; alias stage as transpose buffer
  float(*ldt)[16][33] = (float(*)[16][33])stage;
#pragma unroll
  for (int mf = 0; mf < 2; ++mf)
#pragma unroll
    for (int r = 0; r < 4; ++r)
      ldt[wv][lane & 15][mf * 16 + 4 * (lane >> 4) + r] = hnv[mf][r];
  __syncthreads();
  const int xl = lane & 31;
  const int px = x0 + xl;
  if (px < 56) {
#pragma unroll
    for (int cc = 0; cc < 8; ++cc) {
      const int ch = (lane >> 5) * 8 + cc;
      const float v = ldt[wv][ch][xl];
      out[(((size_t)(b * 16 + t)) * 64 + s * 16 + ch) * 3136 + y * 56 + px] = v;
      if (t == 15)
        out[HL_OFF + ((size_t)(b * 64) + s * 16 + ch) * 3136 + y * 56 + px] = v;
    }
  }
}

extern "C" void kernel_launch(void* const* d_in, const int* in_sizes, int n_in,
                              void* d_out, int out_size, void* d_ws,
                              size_t ws_size, hipStream_t stream) {
  const float* x = (const float*)d_in[0];
  const float* h = (const float*)d_in[1];
  const float* W = (const float*)d_in[2];
  const float* U = (const float*)d_in[3];
  const float* C = (const float*)d_in[4];
  float* out = (float*)d_out;

  u16* ws_u = (u16*)d_ws;
  u16* xpad = ws_u;                       // 2 slots x BIMG
  u16* hpad = xpad + 2 * BIMG;            // BIMG
  u16* rhpad = hpad + BIMG;               // BIMG
  u16* wcat = rhpad + BIMG;               // 221,184
  _Float16* zbuf = (_Float16*)(wcat + 221184);  // 1,835,008 fp16
  float* hstate = (float*)(zbuf + 1835008);     // 1,835,008 f32  (~27 MB total)

  // zero the 4 padded images (borders must stay 0)
  hipMemsetAsync(d_ws, 0, (size_t)4 * BIMG * sizeof(u16), stream);
  wprep_k<<<864, 256, 0, stream>>>(W, U, C, wcat);
  hinit_k<<<dim3(56, 8), 256, 0, stream>>>(h, hpad, hstate);
  xprep0_k<<<448, 256, 0, stream>>>(x, xpad);  // t=0 -> slot 0

  for (int t = 0; t < 16; ++t) {
    stepA_k<<<896, 256, 0, stream>>>(xpad + (size_t)(t & 1) * BIMG, hpad, wcat,
                                     zbuf, rhpad);
    const int nb = (t < 15) ? 1344 : 896;
    stepB_k<<<nb, 256, 0, stream>>>(x, xpad + (size_t)((t + 1) & 1) * BIMG,
                                    xpad + (size_t)(t & 1) * BIMG, rhpad, wcat,
                                    zbuf, hstate, hpad, out, t);
  }
}